// Round 6
// baseline (495.261 us; speedup 1.0000x reference)
//
#include <hip/hip_runtime.h>

#define T_SEQ 2048
#define BATCH 2
#define DMODEL 2048
#define NQH 32
#define NKVH 16
#define HD 128

typedef _Float16 f16;
typedef _Float16 f16x8 __attribute__((ext_vector_type(8)));
typedef _Float16 f16x4 __attribute__((ext_vector_type(4)));
typedef _Float16 f16x2 __attribute__((ext_vector_type(2)));
typedef float f32x4 __attribute__((ext_vector_type(4)));

typedef const __attribute__((address_space(1))) void* gptr_t;
typedef __attribute__((address_space(3))) void* sptr_t;
#define GLDS16(g, l) __builtin_amdgcn_global_load_lds((gptr_t)(g), (sptr_t)(l), 16, 0, 0)

// ---------------- merged transpose+convert: all four W -> f16 transposed ----
__global__ __launch_bounds__(256) void k_transpose_all(const float* __restrict__ Wq,
                                                       const float* __restrict__ Wk,
                                                       const float* __restrict__ Wv,
                                                       const float* __restrict__ Wo,
                                                       f16* __restrict__ WqkvT,
                                                       f16* __restrict__ WoT) {
  __shared__ float tile[32][33];
  const int z = blockIdx.z;
  const float* W;
  f16* WT;
  int N;
  if (z == 0)      { W = Wq; WT = WqkvT;                          N = 4096; }
  else if (z == 1) { W = Wk; WT = WqkvT + (size_t)4096 * 2048;    N = 2048; }
  else if (z == 2) { W = Wv; WT = WqkvT + (size_t)6144 * 2048;    N = 2048; }
  else             { W = Wo; WT = WoT;                            N = 2048; }
  const int K = 2048;
  int n0 = blockIdx.x * 32;
  if (n0 >= N) return;
  int k0 = blockIdx.y * 32;
  int tx = threadIdx.x & 31;
  int ty0 = threadIdx.x >> 5;
  #pragma unroll
  for (int i = 0; i < 4; ++i) {
    int ty = ty0 + i * 8;
    tile[ty][tx] = W[(size_t)(k0 + ty) * N + n0 + tx];
  }
  __syncthreads();
  #pragma unroll
  for (int i = 0; i < 4; ++i) {
    int ty = ty0 + i * 8;
    WT[(size_t)(n0 + ty) * K + k0 + tx] = (f16)tile[tx][ty];
  }
}

// ---------------- 4-phase pipelined GEMM v3 ---------------------------------
// C(M,N) = A(M,K) @ B(K,N), B transposed (N,K). BK=64, 8 waves (WMxWN),
// double-buffered LDS. Per K-tile: 4 phases (kh x m-half), each
// {stage-issue | ds_read quadrant | setprio MFMA} + s_barrier. Single
// vmcnt(0) per K-tile at phase 3 (loads flew >=2 phases). Swizzled slots.
// OM=0: f32 C.  OM=3: fused QKV epilogue (RoPE Q/K, transposed V store).
template<int BM, int BN, int WM, int WN, int OM>
__global__ __launch_bounds__(512, 1) void k_gemm3(const f16* __restrict__ A,
                                                  const f16* __restrict__ BT,
                                                  void* __restrict__ C0,
                                                  f16* __restrict__ Kh,
                                                  f16* __restrict__ VTg,
                                                  const float* __restrict__ cosb,
                                                  const float* __restrict__ sinb,
                                                  int M, int N, int K) {
  constexpr int MR = BM / WM / 16;
  constexpr int MR2 = MR / 2;
  constexpr int NR = BN / WN / 16;
  constexpr int ACH = BM / 64;
  constexpr int BCH = BN / 64;
  __shared__ alignas(16) f16 Al[2][BM * 64];
  __shared__ alignas(16) f16 Bl[2][BN * 64];
  const int tid = threadIdx.x;
  const int lane = tid & 63;
  const int w = tid >> 6;
  const int wr = w / WN, wc = w % WN;
  const int lr = lane & 15, lg = lane >> 4;
  const int nbx = N / BN;
  const int cpx = gridDim.x >> 3;
  const int wg = (blockIdx.x & 7) * cpx + (blockIdx.x >> 3);
  const int m0 = (wg / nbx) * BM, n0 = (wg % nbx) * BN;

#define STAGE_A(BUF, KK)                                                        \
  { _Pragma("unroll")                                                           \
    for (int q = 0; q < ACH; ++q) {                                             \
      int idx = q * 512 + tid; int r = idx >> 3, g = idx & 7;                   \
      GLDS16(A + (size_t)(m0 + r) * K + (KK) + ((g ^ (r & 7)) * 8),             \
             &Al[BUF][idx * 8]);                                                \
    } }
#define STAGE_B(BUF, KK)                                                        \
  { _Pragma("unroll")                                                           \
    for (int q = 0; q < BCH; ++q) {                                             \
      int idx = q * 512 + tid; int r = idx >> 3, g = idx & 7;                   \
      GLDS16(BT + (size_t)(n0 + r) * K + (KK) + ((g ^ (r & 7)) * 8),            \
             &Bl[BUF][idx * 8]);                                                \
    } }
#define LDA8(AF, MH, KH)                                                        \
  { _Pragma("unroll")                                                           \
    for (int i = 0; i < MR2; ++i) {                                             \
      int r = wr * (BM / WM) + ((MH) * MR2 + i) * 16 + lr;                      \
      AF[i] = *(const f16x8*)&Al[buf][r * 64 + ((((KH) * 4 + lg) ^ (r & 7)) * 8)]; \
    } }
#define LDB8(BF, KH)                                                            \
  { _Pragma("unroll")                                                           \
    for (int j = 0; j < NR; ++j) {                                              \
      int r = wc * (BN / WN) + j * 16 + lr;                                     \
      BF[j] = *(const f16x8*)&Bl[buf][r * 64 + ((((KH) * 4 + lg) ^ (r & 7)) * 8)]; \
    } }
#define FMA8(AF, BF, MH)                                                        \
  { __builtin_amdgcn_s_setprio(1);                                              \
    _Pragma("unroll")                                                           \
    for (int i = 0; i < MR2; ++i)                                               \
      _Pragma("unroll")                                                         \
      for (int j = 0; j < NR; ++j)                                              \
        acc[(MH) * MR2 + i][j] =                                                \
          __builtin_amdgcn_mfma_f32_16x16x32_f16(AF[i], BF[j], acc[(MH) * MR2 + i][j], 0, 0, 0); \
    __builtin_amdgcn_s_setprio(0); }
#define PHASE_BAR()                                                             \
  { __builtin_amdgcn_sched_barrier(0); __builtin_amdgcn_s_barrier();            \
    __builtin_amdgcn_sched_barrier(0); }

  f32x4 acc[MR][NR] = {};
  STAGE_A(0, 0);
  STAGE_B(0, 0);
  asm volatile("s_waitcnt vmcnt(0)" ::: "memory");
  __builtin_amdgcn_s_barrier();
  __builtin_amdgcn_sched_barrier(0);

  const int nt = K / 64;
  #pragma unroll 2
  for (int t = 0; t < nt; ++t) {
    const int buf = t & 1;
    f16x8 af[MR2], bf[NR];
    // phase 0: kh=0, mh=0  (+ stage A of t+1)
    if (t + 1 < nt) STAGE_A(buf ^ 1, (t + 1) * 64);
    LDB8(bf, 0);
    LDA8(af, 0, 0);
    FMA8(af, bf, 0);
    PHASE_BAR();
    // phase 1: kh=0, mh=1  (+ stage B of t+1)
    if (t + 1 < nt) STAGE_B(buf ^ 1, (t + 1) * 64);
    LDA8(af, 1, 0);
    FMA8(af, bf, 1);
    PHASE_BAR();
    // phase 2: kh=1, mh=0
    LDB8(bf, 1);
    LDA8(af, 0, 1);
    FMA8(af, bf, 0);
    PHASE_BAR();
    // phase 3: kh=1, mh=1  (+ K-tile boundary drain)
    LDA8(af, 1, 1);
    FMA8(af, bf, 1);
    __builtin_amdgcn_sched_barrier(0);
    asm volatile("s_waitcnt vmcnt(0)" ::: "memory");
    __builtin_amdgcn_s_barrier();
    __builtin_amdgcn_sched_barrier(0);
  }
#undef STAGE_A
#undef STAGE_B
#undef LDA8
#undef LDB8
#undef FMA8
#undef PHASE_BAR

  // ---- epilogue ----
  const int mb = m0 + wr * (BM / WM);
  const int nb = n0 + wc * (BN / WN);
  if constexpr (OM == 0) {
    float* C = (float*)C0;
    #pragma unroll
    for (int i = 0; i < MR; ++i)
      #pragma unroll
      for (int j = 0; j < NR; ++j) {
        int r0 = mb + i * 16 + lg * 4;
        int c = nb + j * 16 + lr;
        #pragma unroll
        for (int r = 0; r < 4; ++r)
          C[(size_t)(r0 + r) * N + c] = acc[i][j][r];
      }
  } else {
    if (n0 < 6144) {  // Q (cols 0..4095) or K (4096..6143): RoPE, row-major f16
      f16* dst = (n0 < 4096) ? (f16*)C0 : Kh;
      const int ncols = (n0 < 4096) ? 4096 : 2048;
      const int coff = (n0 < 4096) ? 0 : 4096;
      #pragma unroll
      for (int i = 0; i < MR; ++i)
        #pragma unroll
        for (int j = 0; j < NR; ++j) {
          int c = nb + j * 16 + lr - coff;
          int jp = (c & 127) >> 1;
          bool odd = (c & 1);
          #pragma unroll
          for (int r = 0; r < 4; ++r) {
            int row = mb + i * 16 + lg * 4 + r;
            int t = row & (T_SEQ - 1);
            float v = acc[i][j][r];
            float pv = __shfl_xor(v, 1);   // partner column (c^1) value
            float cs = cosb[t * 64 + jp], sn = sinb[t * 64 + jp];
            float out = odd ? (pv * sn + v * cs) : (v * cs - pv * sn);
            dst[(size_t)row * ncols + c] = (f16)out;
          }
        }
    } else {          // V (cols 6144..8191): transposed per head VT[b][h][d][t]
      #pragma unroll
      for (int i = 0; i < MR; ++i)
        #pragma unroll
        for (int j = 0; j < NR; ++j) {
          int c = nb + j * 16 + lr - 6144;
          int head = c >> 7, d = c & 127;
          int row0 = mb + i * 16 + lg * 4;
          int bb = row0 >> 11, t0 = row0 & (T_SEQ - 1);
          f16x4 zv;
          #pragma unroll
          for (int r = 0; r < 4; ++r) zv[r] = (f16)acc[i][j][r];
          *(f16x4*)(VTg + ((size_t)(bb * NKVH + head) * HD + d) * T_SEQ + t0) = zv;
        }
    }
  }
}

// ---------------- lambda = sigmoid(x @ Wlam) + x->f16 convert (fused) -------
__global__ __launch_bounds__(256) void k_lambda_conv(const float* __restrict__ x,
                                                     const float* __restrict__ Wlam,
                                                     float* __restrict__ lam,
                                                     f16* __restrict__ xh) {
  int row = blockIdx.x;
  const float* xr = x + (size_t)row * DMODEL;
  const int e = threadIdx.x * 8;            // 256 threads x 8 = 2048
  const float4* xp = (const float4*)(xr + e);
  float4 a = xp[0], b2 = xp[1];
  float xv[8] = {a.x, a.y, a.z, a.w, b2.x, b2.y, b2.z, b2.w};
  f16x8 hv;
  #pragma unroll
  for (int j = 0; j < 8; ++j) hv[j] = (f16)xv[j];
  *(f16x8*)(xh + (size_t)row * DMODEL + e) = hv;
  float acc[16];
  #pragma unroll
  for (int h = 0; h < 16; ++h) acc[h] = 0.f;
  #pragma unroll
  for (int j = 0; j < 8; ++j) {
    const float4* wp = (const float4*)(Wlam + (size_t)(e + j) * 16);
    #pragma unroll
    for (int g = 0; g < 4; ++g) {
      float4 wv = wp[g];
      acc[g * 4 + 0] += xv[j] * wv.x; acc[g * 4 + 1] += xv[j] * wv.y;
      acc[g * 4 + 2] += xv[j] * wv.z; acc[g * 4 + 3] += xv[j] * wv.w;
    }
  }
  #pragma unroll
  for (int h = 0; h < 16; ++h)
    for (int off = 32; off > 0; off >>= 1)
      acc[h] += __shfl_down(acc[h], off);
  __shared__ float part[4][16];
  int lane = threadIdx.x & 63, w = threadIdx.x >> 6;
  if (lane == 0) {
    #pragma unroll
    for (int h = 0; h < 16; ++h) part[w][h] = acc[h];
  }
  __syncthreads();
  if (threadIdx.x < 16) {
    float s = part[0][threadIdx.x] + part[1][threadIdx.x] + part[2][threadIdx.x] + part[3][threadIdx.x];
    lam[row * 16 + threadIdx.x] = 1.f / (1.f + __expf(-s));
  }
}

// ---------------- causal flash attention v4 + setprio ------------------------
__global__ __launch_bounds__(256, 4) void k_attn4(const f16* __restrict__ Q,
                                                  const f16* __restrict__ K,
                                                  const f16* __restrict__ VT,
                                                  f16* __restrict__ O) {
  __shared__ f16 Kl[64 * 128];
  __shared__ f16 Vl[128 * 64];
  __shared__ f16 Pl[4][16][40];
  const int tid = threadIdx.x;
  const int lane = tid & 63;
  const int w = tid >> 6;
  const int lr = lane & 15, lg = lane >> 4;
  const int flat = blockIdx.x;
  const int xcd = flat & 7;
  const int work = xcd * 128 + (flat >> 3);
  const int grp = work >> 5;
  const int within = work & 31;
  const int b = grp >> 4, hkv = grp & 15;
  const int h = hkv * 2 + (within >> 4);
  const int bx = within & 15;
  const f16* Kg  = K  + (size_t)b * T_SEQ * (NKVH * HD) + hkv * HD;
  const f16* VTg = VT + (size_t)(b * NKVH + hkv) * HD * T_SEQ;
  const float sc = 0.08838834764831845f;

  #pragma unroll 1
  for (int half = 0; half < 2; ++half) {
    const int qt = half ? (31 - bx) : bx;
    const int qb = qt * 64;
    const int qw = qb + w * 16;
    const int qrow = qw + lr;
    f16x8 qf[4];
    {
      const f16* qp = Q + (size_t)(b * T_SEQ + qrow) * (NQH * HD) + h * HD + lg * 8;
      #pragma unroll
      for (int c = 0; c < 4; ++c) qf[c] = *(const f16x8*)(qp + c * 32);
    }
    f32x4 o[8] = {};
    float mi = -1e30f, li = 0.f;

    const int nt = qt + 1;
    #pragma unroll 1
    for (int t = 0; t < nt; ++t) {
      const int s0 = t * 64;
      #pragma unroll
      for (int qq = 0; qq < 4; ++qq) {
        int idx = qq * 256 + tid;
        int r = idx >> 4, g = idx & 15;
        GLDS16(Kg + (size_t)(s0 + r) * (NKVH * HD) + (g ^ (r & 7)) * 8, &Kl[idx * 8]);
      }
      #pragma unroll
      for (int qq = 0; qq < 4; ++qq) {
        int idx = qq * 256 + tid;
        int d = idx >> 3, g = idx & 7;
        GLDS16(VTg + (size_t)d * T_SEQ + s0 + (g ^ (d & 7)) * 8, &Vl[idx * 8]);
      }
      __syncthreads();

      f32x4 sf[4] = {};
      __builtin_amdgcn_s_setprio(1);
      #pragma unroll
      for (int c = 0; c < 4; ++c) {
        #pragma unroll
        for (int nb = 0; nb < 4; ++nb) {
          f16x8 kf = *(const f16x8*)&Kl[(((nb * 16 + lr) * 16) + ((c * 4 + lg) ^ (lr & 7))) * 8];
          sf[nb] = __builtin_amdgcn_mfma_f32_16x16x32_f16(kf, qf[c], sf[nb], 0, 0, 0);
        }
      }
      __builtin_amdgcn_s_setprio(0);
      float v[16];
      #pragma unroll
      for (int nb = 0; nb < 4; ++nb)
        #pragma unroll
        for (int rr = 0; rr < 4; ++rr) {
          float x = sf[nb][rr] * sc;
          int kv = s0 + nb * 16 + lg * 4 + rr;
          v[nb * 4 + rr] = (kv > qrow) ? -1e30f : x;
        }
      float pm = v[0];
      #pragma unroll
      for (int i = 1; i < 16; ++i) pm = fmaxf(pm, v[i]);
      pm = fmaxf(pm, __shfl_xor(pm, 16));
      pm = fmaxf(pm, __shfl_xor(pm, 32));
      float mnew = fmaxf(mi, pm);
      float a = __expf(mi - mnew);
      mi = mnew;
      float rs = 0.f;
      #pragma unroll
      for (int i = 0; i < 16; ++i) { float p = __expf(v[i] - mnew); v[i] = p; rs += p; }
      rs += __shfl_xor(rs, 16);
      rs += __shfl_xor(rs, 32);
      li = a * li + rs;
      float ab[4];
      #pragma unroll
      for (int rr = 0; rr < 4; ++rr) ab[rr] = __shfl(a, lg * 4 + rr);
      #pragma unroll
      for (int j = 0; j < 8; ++j)
        #pragma unroll
        for (int rr = 0; rr < 4; ++rr) o[j][rr] *= ab[rr];
      #pragma unroll
      for (int ks = 0; ks < 2; ++ks) {
        #pragma unroll
        for (int nb2 = 0; nb2 < 2; ++nb2) {
          int nb = ks * 2 + nb2;
          f16x4 pk;
          #pragma unroll
          for (int rr = 0; rr < 4; ++rr) pk[rr] = (f16)v[nb * 4 + rr];
          *(f16x4*)&Pl[w][lr][nb2 * 16 + lg * 4] = pk;
        }
        f16x8 pa = *(const f16x8*)&Pl[w][lr][lg * 8];
        __builtin_amdgcn_s_setprio(1);
        #pragma unroll
        for (int j = 0; j < 8; ++j) {
          f16x8 vbj = *(const f16x8*)&Vl[(((j * 16 + lr) * 8) + ((ks * 4 + lg) ^ (lr & 7))) * 8];
          o[j] = __builtin_amdgcn_mfma_f32_16x16x32_f16(pa, vbj, o[j], 0, 0, 0);
        }
        __builtin_amdgcn_s_setprio(0);
      }
      __syncthreads();
    }
    float lib[4];
    #pragma unroll
    for (int rr = 0; rr < 4; ++rr) lib[rr] = 1.f / __shfl(li, lg * 4 + rr);
    #pragma unroll
    for (int j = 0; j < 8; ++j)
      #pragma unroll
      for (int rr = 0; rr < 4; ++rr) {
        float vv = o[j][rr] * lib[rr];
        O[(size_t)(b * T_SEQ + qw + lg * 4 + rr) * (NQH * HD) + h * HD + j * 16 + lr] = (f16)vv;
      }
  }
}

// ---------------- differential combine: Z = attn_even - lam * attn_odd ------
__global__ void k_combine(const f16* __restrict__ attn, const float* __restrict__ lam,
                          f16* __restrict__ Z) {
  int idx = blockIdx.x * blockDim.x + threadIdx.x;
  int d4 = idx & 31;
  int tmp = idx >> 5;
  int h = tmp & 15;
  int row = tmp >> 4;
  if (row >= BATCH * T_SEQ) return;
  float lv = lam[row * 16 + h];
  f16x4 a1 = *(const f16x4*)(attn + (size_t)row * 4096 + (2 * h) * 128 + d4 * 4);
  f16x4 a2 = *(const f16x4*)(attn + (size_t)row * 4096 + (2 * h + 1) * 128 + d4 * 4);
  f16x4 z;
  #pragma unroll
  for (int e = 0; e < 4; ++e) z[e] = (f16)((float)a1[e] - lv * (float)a2[e]);
  *(f16x4*)(Z + (size_t)row * 2048 + h * 128 + d4 * 4) = z;
}

extern "C" void kernel_launch(void* const* d_in, const int* in_sizes, int n_in,
                              void* d_out, int out_size, void* d_ws, size_t ws_size,
                              hipStream_t stream) {
  const float* x    = (const float*)d_in[0];
  const float* cosb = (const float*)d_in[1];
  const float* sinb = (const float*)d_in[2];
  const float* Wq   = (const float*)d_in[3];
  const float* Wk   = (const float*)d_in[4];
  const float* Wv   = (const float*)d_in[5];
  const float* Wo   = (const float*)d_in[6];
  const float* Wlam = (const float*)d_in[7];

  char* ws = (char*)d_ws;
  f16*  xh     = (f16*)(ws);                      // 16 MB  x in f16
  f16*  WqkvT  = (f16*)(ws + 16777216);           // 32 MB  [Wq^T; Wk^T; Wv^T] (8192,2048)
  f16*  WoT    = (f16*)(ws + 50331648);           //  8 MB
  f16*  Qh     = (f16*)(ws + 58720256);           // 32 MB  (4096,4096) rope'd
  f16*  Kh     = (f16*)(ws + 92274688);           // 16 MB  (4096,2048) rope'd
  f16*  VTg    = (f16*)(ws + 109051904);          // 16 MB  (32 head-slices,128,2048)
  f16*  At     = (f16*)(ws + 125829120);          // 32 MB  attn out (4096,4096)
  f16*  Zh     = (f16*)(ws + 159383552);          // 16 MB  (4096,2048)
  float* lam   = (float*)(ws + 176160768);        // 256 KB (4096,16)

  k_transpose_all<<<dim3(128, 64, 4), 256, 0, stream>>>(Wq, Wk, Wv, Wo, WqkvT, WoT);
  k_lambda_conv<<<4096, 256, 0, stream>>>(x, Wlam, lam, xh);

  // fused QKV projection + RoPE + V-transpose: M=4096, N=8192, K=2048
  k_gemm3<256, 256, 2, 4, 3><<<512, 512, 0, stream>>>(xh, WqkvT, Qh, Kh, VTg,
                                                      cosb, sinb, 4096, 8192, 2048);

  k_attn4<<<1024, 256, 0, stream>>>(Qh, Kh, VTg, At);

  k_combine<<<(BATCH * T_SEQ * 16 * 32) / 256, 256, 0, stream>>>(At, lam, Zh);

  // output projection: M=4096, N=2048, K=2048 -> f32 d_out
  k_gemm3<256, 128, 4, 2, 0><<<256, 512, 0, stream>>>(Zh, WoT, d_out, nullptr, nullptr,
                                                      nullptr, nullptr, 4096, 2048, 2048);
}